// Round 1
// baseline (392.105 us; speedup 1.0000x reference)
//
#include <hip/hip_runtime.h>
#include <math.h>

#define N_NODES 8192
#define F_IN 128
#define DH 64
#define H_HEADS 2
#define MAX_E 256

// ---------------------------------------------------------------------------
// Kernel 1: h[h,n,d] = sum_f X[n,f] * W[h,f,d];  s_neigh[h,n] = h[h,n,:].a_neigh[h,:]
// One block (128 threads) per node. Wave 0 = head 0, wave 1 = head 1.
// ---------------------------------------------------------------------------
__global__ __launch_bounds__(128) void gat_transform(
    const float* __restrict__ X, const float* __restrict__ W,
    const float* __restrict__ a_neigh, float* __restrict__ hbuf,
    float* __restrict__ sneigh) {
  const int n = blockIdx.x;
  const int t = threadIdx.x;       // 0..127
  const int head = t >> 6;         // wave id
  const int d = t & 63;

  __shared__ float xs[F_IN];
  xs[t] = X[(size_t)n * F_IN + t];
  __syncthreads();

  const float* Wc = W + (size_t)head * F_IN * DH + d;  // W[head][f][d], stride DH
  float acc = 0.f;
#pragma unroll
  for (int f = 0; f < F_IN; ++f) acc = fmaf(xs[f], Wc[(size_t)f * DH], acc);

  hbuf[((size_t)head * N_NODES + n) * DH + d] = acc;

  // s_neigh: reduce acc * a_neigh over the 64 lanes of this wave (one head)
  float p = acc * a_neigh[head * DH + d];
#pragma unroll
  for (int off = 32; off > 0; off >>= 1) p += __shfl_xor(p, off, 64);
  if (d == 0) sneigh[head * N_NODES + n] = p;
}

// ---------------------------------------------------------------------------
// Kernel 2: per row i — extract edges from adj row, softmax over s_neigh[j]
// (s_self[i] cancels; masked exp underflows to 0), weighted gather of h.
// One block (256 threads) per row.
// ---------------------------------------------------------------------------
__global__ __launch_bounds__(256) void gat_attn(
    const float* __restrict__ adj, const float* __restrict__ hbuf,
    const float* __restrict__ sneigh, const float* __restrict__ bias,
    float* __restrict__ out) {
  const int i = blockIdx.x;
  const int t = threadIdx.x;

  __shared__ int eidx[MAX_E];
  __shared__ float wexp[H_HEADS][MAX_E];
  __shared__ int ecnt;
  __shared__ float red0[256], red1[256];

  if (t == 0) ecnt = 0;
  __syncthreads();

  // --- scan adjacency row (coalesced float4), push nonzero column indices ---
  const float4* row = (const float4*)(adj + (size_t)i * N_NODES);
#pragma unroll
  for (int b = t; b < N_NODES / 4; b += 256) {
    float4 v = row[b];
    int j0 = b * 4;
    if (v.x > 0.5f) { int e = atomicAdd(&ecnt, 1); if (e < MAX_E) eidx[e] = j0; }
    if (v.y > 0.5f) { int e = atomicAdd(&ecnt, 1); if (e < MAX_E) eidx[e] = j0 + 1; }
    if (v.z > 0.5f) { int e = atomicAdd(&ecnt, 1); if (e < MAX_E) eidx[e] = j0 + 2; }
    if (v.w > 0.5f) { int e = atomicAdd(&ecnt, 1); if (e < MAX_E) eidx[e] = j0 + 3; }
  }
  __syncthreads();
  const int deg = min(ecnt, MAX_E);   // ~33 avg; every row has its self-loop

  // --- per-head max of s_neigh over edges ---
  float m0 = -1e30f, m1 = -1e30f;
  for (int e = t; e < deg; e += 256) {
    int j = eidx[e];
    m0 = fmaxf(m0, sneigh[j]);
    m1 = fmaxf(m1, sneigh[N_NODES + j]);
  }
  red0[t] = m0; red1[t] = m1;
  __syncthreads();
#pragma unroll
  for (int s = 128; s > 0; s >>= 1) {
    if (t < s) {
      red0[t] = fmaxf(red0[t], red0[t + s]);
      red1[t] = fmaxf(red1[t], red1[t + s]);
    }
    __syncthreads();
  }
  const float M0 = red0[0], M1 = red1[0];
  __syncthreads();

  // --- exp weights (into LDS) + per-head partition sum ---
  float z0 = 0.f, z1 = 0.f;
  for (int e = t; e < deg; e += 256) {
    int j = eidx[e];
    float w0 = __expf(sneigh[j] - M0);
    float w1 = __expf(sneigh[N_NODES + j] - M1);
    wexp[0][e] = w0; wexp[1][e] = w1;
    z0 += w0; z1 += w1;
  }
  red0[t] = z0; red1[t] = z1;
  __syncthreads();
#pragma unroll
  for (int s = 128; s > 0; s >>= 1) {
    if (t < s) {
      red0[t] += red0[t + s];
      red1[t] += red1[t + s];
    }
    __syncthreads();
  }
  const float Z0 = red0[0], Z1 = red1[0];

  // --- weighted gather of h, one output channel per thread (t < 128) ---
  if (t < 128) {
    const int head = t >> 6;
    const int dd = t & 63;
    const float* hb = hbuf + (size_t)head * N_NODES * DH + dd;
    const float* wl = wexp[head];
    float ctx = 0.f;
    for (int e = 0; e < deg; ++e) {
      ctx = fmaf(wl[e], hb[(size_t)eidx[e] * DH], ctx);
    }
    float val = ctx / (head ? Z1 : Z0) + bias[t];
    out[(size_t)i * (H_HEADS * DH) + t] = val > 0.f ? val : expm1f(val);
  }
}

extern "C" void kernel_launch(void* const* d_in, const int* in_sizes, int n_in,
                              void* d_out, int out_size, void* d_ws, size_t ws_size,
                              hipStream_t stream) {
  const float* X       = (const float*)d_in[0];  // [N, F_IN]
  const float* adj     = (const float*)d_in[1];  // [N, N]
  const float* W       = (const float*)d_in[2];  // [H, F_IN, DH]
  // d_in[3] = a_self — mathematically cancels in the row softmax, unused
  const float* a_neigh = (const float*)d_in[4];  // [H, DH]
  const float* bias    = (const float*)d_in[5];  // [H*DH]
  float* out = (float*)d_out;

  float* hbuf   = (float*)d_ws;                              // [H, N, DH] = 4 MB
  float* sneigh = hbuf + (size_t)H_HEADS * N_NODES * DH;     // [H, N] = 64 KB

  gat_transform<<<N_NODES, 128, 0, stream>>>(X, W, a_neigh, hbuf, sneigh);
  gat_attn<<<N_NODES, 256, 0, stream>>>(adj, hbuf, sneigh, bias, out);
}